// Round 12
// baseline (342.419 us; speedup 1.0000x reference)
//
#include <hip/hip_runtime.h>
#include <cstdint>
#include <cstddef>

#define T_SEQ 4096
#define BATCH 2
#define HIDDEN 1024
#define NHEAD 8
#define DKV 128
#define BT (BATCH * T_SEQ)   // 8192
#define NCH 64               // chunks per batch
#define CHUNK_L 64
#define QSCALE 0.08838834764831845f
#define SCALE_P 1024.0f
#define SCALE_O 8192.0f
#define OEPS 0.7071067811865476f

typedef _Float16 half8 __attribute__((ext_vector_type(8)));
typedef float floatx4 __attribute__((ext_vector_type(4)));

union HBits { _Float16 h; unsigned short u; };

// ---------------------------------------------------------------------------
// fp32 -> fp16 cast, 8 elements/thread
// ---------------------------------------------------------------------------
__global__ void cast_f32_f16(const float* __restrict__ X, _Float16* __restrict__ Y, int n8)
{
    int idx = blockIdx.x * 256 + threadIdx.x;
    if (idx < n8) {
        float4 a = ((const float4*)X)[idx * 2];
        float4 b = ((const float4*)X)[idx * 2 + 1];
        half8 h = { (_Float16)a.x, (_Float16)a.y, (_Float16)a.z, (_Float16)a.w,
                    (_Float16)b.x, (_Float16)b.y, (_Float16)b.z, (_Float16)b.w };
        *(half8*)&Y[idx * 8] = h;
    }
}

// 8 weight tensors in one launch; blockIdx.y selects.
__global__ void cast8_f32_f16(const float* __restrict__ s0, const float* __restrict__ s1,
                              const float* __restrict__ s2, const float* __restrict__ s3,
                              const float* __restrict__ s4, const float* __restrict__ s5,
                              const float* __restrict__ s6, const float* __restrict__ s7,
                              _Float16* __restrict__ d0, _Float16* __restrict__ d1,
                              _Float16* __restrict__ d2, _Float16* __restrict__ d3,
                              _Float16* __restrict__ d4, _Float16* __restrict__ d5,
                              _Float16* __restrict__ d6, _Float16* __restrict__ d7,
                              int nbig, int nsmall)
{
    int sel = blockIdx.y;
    const float* src; _Float16* dst; int n8;
    switch (sel) {
        case 0: src = s0; dst = d0; n8 = nbig; break;
        case 1: src = s1; dst = d1; n8 = nbig; break;
        case 2: src = s2; dst = d2; n8 = nbig; break;
        case 3: src = s3; dst = d3; n8 = nbig; break;
        case 4: src = s4; dst = d4; n8 = nsmall; break;
        case 5: src = s5; dst = d5; n8 = nsmall; break;
        case 6: src = s6; dst = d6; n8 = nsmall; break;
        default: src = s7; dst = d7; n8 = nsmall; break;
    }
    int idx = blockIdx.x * 256 + threadIdx.x;
    if (idx < n8) {
        float4 u = ((const float4*)src)[idx * 2];
        float4 v = ((const float4*)src)[idx * 2 + 1];
        half8 h = { (_Float16)u.x, (_Float16)u.y, (_Float16)u.z, (_Float16)u.w,
                    (_Float16)v.x, (_Float16)v.y, (_Float16)v.z, (_Float16)v.w };
        *(half8*)&dst[idx * 8] = h;
    }
}

// ---------------------------------------------------------------------------
// GEMM (NT) fp16 MFMA, fp16 out: 128x128 tile, BK=64, 4 waves, XOR-swizzled
// LDS columns. Proven R8 structure: ~747 TF, 0 bank conflicts.
// ---------------------------------------------------------------------------
__global__ __launch_bounds__(256) void gemm_nt_f16_h16(const _Float16* __restrict__ A,
                                                       const _Float16* __restrict__ W,
                                                       _Float16* __restrict__ C,
                                                       int M, int N, int K)
{
    __shared__ _Float16 As[128 * 64];
    __shared__ _Float16 Ws[128 * 64];
    const int bm = blockIdx.y * 128;
    const int bn = blockIdx.x * 128;
    const int tid = threadIdx.x;
    const int w = tid >> 6;
    const int l = tid & 63;
    const int wm = (w >> 1) * 64;
    const int wn = (w & 1) * 64;
    const int lane16 = l & 15;
    const int quad = l >> 4;
    const int srow = w * 8 + (l >> 3);
    const int skh = ((l & 7) ^ (l >> 3)) * 8;
    const int rsw = lane16 & 7;

    floatx4 acc[4][4];
#pragma unroll
    for (int i = 0; i < 4; ++i)
#pragma unroll
        for (int j = 0; j < 4; ++j)
            acc[i][j] = (floatx4){0.f, 0.f, 0.f, 0.f};

    for (int k0 = 0; k0 < K; k0 += 64) {
#pragma unroll
        for (int c = 0; c < 4; ++c) {
            int row = c * 32 + srow;
            const _Float16* ga = A + (size_t)(bm + row) * K + k0 + skh;
            const _Float16* gw = W + (size_t)(bn + row) * K + k0 + skh;
            __builtin_amdgcn_global_load_lds(
                (const __attribute__((address_space(1))) void*)ga,
                (__attribute__((address_space(3))) void*)(As + c * 2048 + w * 512), 16, 0, 0);
            __builtin_amdgcn_global_load_lds(
                (const __attribute__((address_space(1))) void*)gw,
                (__attribute__((address_space(3))) void*)(Ws + c * 2048 + w * 512), 16, 0, 0);
        }
        __syncthreads();

#pragma unroll
        for (int s = 0; s < 2; ++s) {
            const int pc = (((s * 4 + quad) ^ rsw)) * 8;
            half8 a[4], b[4];
#pragma unroll
            for (int i = 0; i < 4; ++i) {
                a[i] = *(const half8*)&As[(wm + i * 16 + lane16) * 64 + pc];
                b[i] = *(const half8*)&Ws[(wn + i * 16 + lane16) * 64 + pc];
            }
#pragma unroll
            for (int i = 0; i < 4; ++i)
#pragma unroll
                for (int j = 0; j < 4; ++j)
                    acc[i][j] = __builtin_amdgcn_mfma_f32_16x16x32_f16(a[i], b[j], acc[i][j], 0, 0, 0);
        }
        __syncthreads();
    }
#pragma unroll
    for (int i = 0; i < 4; ++i)
#pragma unroll
        for (int j = 0; j < 4; ++j)
#pragma unroll
            for (int r = 0; r < 4; ++r)
                C[(size_t)(bm + wm + i * 16 + quad * 4 + r) * N + bn + wn + j * 16 + lane16] =
                    (_Float16)acc[i][j][r];
}

// ---------------------------------------------------------------------------
// Same BK=64 structure, fp32 out with scale (final projection; undoes SCALE_O).
// ---------------------------------------------------------------------------
__global__ __launch_bounds__(256) void gemm_nt_f16_f32(const _Float16* __restrict__ A,
                                                       const _Float16* __restrict__ W,
                                                       float* __restrict__ C,
                                                       int M, int N, int K, float scale)
{
    __shared__ _Float16 As[128 * 64];
    __shared__ _Float16 Ws[128 * 64];
    const int bm = blockIdx.y * 128;
    const int bn = blockIdx.x * 128;
    const int tid = threadIdx.x;
    const int w = tid >> 6;
    const int l = tid & 63;
    const int wm = (w >> 1) * 64;
    const int wn = (w & 1) * 64;
    const int lane16 = l & 15;
    const int quad = l >> 4;
    const int srow = w * 8 + (l >> 3);
    const int skh = ((l & 7) ^ (l >> 3)) * 8;
    const int rsw = lane16 & 7;

    floatx4 acc[4][4];
#pragma unroll
    for (int i = 0; i < 4; ++i)
#pragma unroll
        for (int j = 0; j < 4; ++j)
            acc[i][j] = (floatx4){0.f, 0.f, 0.f, 0.f};

    for (int k0 = 0; k0 < K; k0 += 64) {
#pragma unroll
        for (int c = 0; c < 4; ++c) {
            int row = c * 32 + srow;
            const _Float16* ga = A + (size_t)(bm + row) * K + k0 + skh;
            const _Float16* gw = W + (size_t)(bn + row) * K + k0 + skh;
            __builtin_amdgcn_global_load_lds(
                (const __attribute__((address_space(1))) void*)ga,
                (__attribute__((address_space(3))) void*)(As + c * 2048 + w * 512), 16, 0, 0);
            __builtin_amdgcn_global_load_lds(
                (const __attribute__((address_space(1))) void*)gw,
                (__attribute__((address_space(3))) void*)(Ws + c * 2048 + w * 512), 16, 0, 0);
        }
        __syncthreads();

#pragma unroll
        for (int s = 0; s < 2; ++s) {
            const int pc = (((s * 4 + quad) ^ rsw)) * 8;
            half8 a[4], b[4];
#pragma unroll
            for (int i = 0; i < 4; ++i) {
                a[i] = *(const half8*)&As[(wm + i * 16 + lane16) * 64 + pc];
                b[i] = *(const half8*)&Ws[(wn + i * 16 + lane16) * 64 + pc];
            }
#pragma unroll
            for (int i = 0; i < 4; ++i)
#pragma unroll
                for (int j = 0; j < 4; ++j)
                    acc[i][j] = __builtin_amdgcn_mfma_f32_16x16x32_f16(a[i], b[j], acc[i][j], 0, 0, 0);
        }
        __syncthreads();
    }
#pragma unroll
    for (int i = 0; i < 4; ++i)
#pragma unroll
        for (int j = 0; j < 4; ++j)
#pragma unroll
            for (int r = 0; r < 4; ++r)
                C[(size_t)(bm + wm + i * 16 + quad * 4 + r) * N + bn + wn + j * 16 + lane16] =
                    acc[i][j][r] * scale;
}

// ---------------------------------------------------------------------------
// Conv + SiLU for V, writing TRANSPOSED: vT[b*1024 + d][t]  (fp16).
// grid.x = 2048 = 64 ttiles * 16 dtiles * 2 batch.
// ---------------------------------------------------------------------------
__global__ __launch_bounds__(256) void conv_silu_T(const _Float16* __restrict__ X, int ldx,
                                                   const float* __restrict__ Wc,
                                                   _Float16* __restrict__ VT)
{
    __shared__ _Float16 xs[67 * 64];
    const int bx = blockIdx.x;
    const int t0 = (bx & 63) * 64;
    const int dt = ((bx >> 6) & 15) * 64;
    const int z = bx >> 10;
    const int tid = threadIdx.x;

#pragma unroll
    for (int i = 0; i < 3; ++i) {
        int p = tid + 256 * i;
        if (p < 536) {
            int row = p >> 3, d8 = (p & 7) * 8;
            int t = t0 - 3 + row;
            half8 v;
            if (t >= 0)
                v = *(const half8*)&X[((size_t)z * T_SEQ + t) * ldx + dt + d8];
            else
                v = (half8){0, 0, 0, 0, 0, 0, 0, 0};
            *(half8*)&xs[row * 64 + d8] = v;
        }
    }
    __syncthreads();

    const int d = tid & 63;
    const int dg = dt + d;
    float4 w = *(const float4*)&Wc[dg * 4];
#pragma unroll
    for (int u = 0; u < 2; ++u) {
        int tg = (tid >> 6) + u * 4;
        half8 o;
#pragma unroll
        for (int s = 0; s < 8; ++s) {
            int base = (tg * 8 + s + 3) * 64 + d;
            float acc = (float)xs[base] * w.w
                      + (float)xs[base - 64] * w.z
                      + (float)xs[base - 128] * w.y
                      + (float)xs[base - 192] * w.x;
            o[s] = (_Float16)(acc / (1.f + __expf(-acc)));
        }
        *(half8*)&VT[((size_t)z * HIDDEN + dg) * T_SEQ + t0 + tg * 8] = o;
    }
}

// ---------------------------------------------------------------------------
// FUSED conv+SiLU + feature map (q/k via blockIdx.z).
// Stage 67x128 input window of qkvlin -> LDS, conv+silu in registers ->
// ds_write into MFMA staging tile xs[kstep][row][32] -> dual GEMM + hadamard.
// Eliminates the qc16/kc16 global round trip (64 MB).
// ---------------------------------------------------------------------------
#define XIN_LD 136   // 67 rows x 136 halfs (16B-aligned rows, bank-spread)
__global__ __launch_bounds__(256) void convfm(const _Float16* __restrict__ QKV, int ldx,
                                              const float* __restrict__ Wcq,
                                              const float* __restrict__ Wck,
                                              const _Float16* __restrict__ Wfm,  // 4x16384
                                              const float* __restrict__ Bq1,
                                              const float* __restrict__ Bq2,
                                              const float* __restrict__ Bk1,
                                              const float* __restrict__ Bk2,
                                              _Float16* __restrict__ OUTq,
                                              _Float16* __restrict__ OUTk)
{
    const int sel = blockIdx.z;
    const float* Wc = sel ? Wck : Wcq;
    const _Float16* W1h = Wfm + (sel ? 2 * 16384 : 0);
    const _Float16* W2h = Wfm + (sel ? 3 * 16384 : 16384);
    const float* B1 = sel ? Bk1 : Bq1;
    const float* B2 = sel ? Bk2 : Bq2;
    _Float16* OUT = sel ? OUTk : OUTq;

    __shared__ _Float16 xin[67 * XIN_LD];    // input window (t0-3 .. t0+63) x 128
    __shared__ _Float16 xs[4 * 64 * 32];     // conv output, MFMA staging layout
    const int t0 = blockIdx.x * 64;
    const int h = blockIdx.y;
    const int tid = threadIdx.x;
    const int w = tid >> 6;
    const int l = tid & 63;
    const int lane16 = l & 15;
    const int quad = l >> 4;
    const bool batch_start = (t0 & (T_SEQ - 1)) == 0;

    // ---- stage input window: 67 rows x 16 col-groups = 1072 half8 ----
    for (int p = tid; p < 67 * 16; p += 256) {
        int row = p >> 4, cg = p & 15;
        half8 v;
        if (batch_start && row < 3)
            v = (half8){0, 0, 0, 0, 0, 0, 0, 0};
        else
            v = *(const half8*)&QKV[(size_t)(t0 - 3 + row) * ldx + sel * HIDDEN + h * DKV + cg * 8];
        *(half8*)&xin[row * XIN_LD + cg * 8] = v;
    }
    __syncthreads();

    // ---- conv + silu: thread = (row = tid>>2, dgrp = (tid&3) + 4u) ----
    {
        const int row = tid >> 2;
#pragma unroll
        for (int u = 0; u < 4; ++u) {
            const int d0 = ((tid & 3) + 4 * u) * 8;
            half8 x0 = *(const half8*)&xin[(row + 3) * XIN_LD + d0];
            half8 x1 = *(const half8*)&xin[(row + 2) * XIN_LD + d0];
            half8 x2 = *(const half8*)&xin[(row + 1) * XIN_LD + d0];
            half8 x3 = *(const half8*)&xin[(row + 0) * XIN_LD + d0];
            half8 o;
#pragma unroll
            for (int e = 0; e < 8; ++e) {
                float4 wv = *(const float4*)&Wc[(h * DKV + d0 + e) * 4];
                float acc = fmaf((float)x0[e], wv.w,
                            fmaf((float)x1[e], wv.z,
                            fmaf((float)x2[e], wv.y, (float)x3[e] * wv.x)));
                o[e] = (_Float16)(acc / (1.f + __expf(-acc)));
            }
            *(half8*)&xs[u * 2048 + row * 32 + (d0 & 31)] = o;
        }
    }
    __syncthreads();

    // ---- dual GEMM + hadamard (identical to fm_mfma2 body) ----
    floatx4 acc1[4][2], acc2[4][2];
#pragma unroll
    for (int i = 0; i < 4; ++i)
#pragma unroll
        for (int j = 0; j < 2; ++j) {
            acc1[i][j] = (floatx4){0.f, 0.f, 0.f, 0.f};
            acc2[i][j] = (floatx4){0.f, 0.f, 0.f, 0.f};
        }

#pragma unroll
    for (int s = 0; s < 4; ++s) {
        half8 a[4];
#pragma unroll
        for (int mt = 0; mt < 4; ++mt)
            a[mt] = *(const half8*)&xs[s * 2048 + (mt * 16 + lane16) * 32 + quad * 8];
#pragma unroll
        for (int nt = 0; nt < 2; ++nt) {
            int e = w * 32 + nt * 16 + lane16;
            half8 b1 = *(const half8*)&W1h[(size_t)e * DKV + s * 32 + quad * 8];
            half8 b2 = *(const half8*)&W2h[(size_t)e * DKV + s * 32 + quad * 8];
#pragma unroll
            for (int mt = 0; mt < 4; ++mt) {
                acc1[mt][nt] = __builtin_amdgcn_mfma_f32_16x16x32_f16(a[mt], b1, acc1[mt][nt], 0, 0, 0);
                acc2[mt][nt] = __builtin_amdgcn_mfma_f32_16x16x32_f16(a[mt], b2, acc2[mt][nt], 0, 0, 0);
            }
        }
    }

#pragma unroll
    for (int nt = 0; nt < 2; ++nt) {
        int e = w * 32 + nt * 16 + lane16;
        float b1v = B1[e], b2v = B2[e];
#pragma unroll
        for (int mt = 0; mt < 4; ++mt)
#pragma unroll
            for (int r = 0; r < 4; ++r) {
                float o = (acc1[mt][nt][r] + b1v) * (acc2[mt][nt][r] + b2v);
                OUT[(size_t)(t0 + mt * 16 + quad * 4 + r) * HIDDEN + h * DKV + e] = (_Float16)o;
            }
    }
}

// ---------------------------------------------------------------------------
// Per-chunk S^T[dv][dk] = sum_j V[j][dv] K[j][dk], MFMA. fp16 out.
// ---------------------------------------------------------------------------
__global__ __launch_bounds__(256) void ktv_mfma(const _Float16* __restrict__ Kf,
                                                const _Float16* __restrict__ VT,
                                                _Float16* __restrict__ G16)
{
    __shared__ _Float16 kt[128 * 72];
    const int c = blockIdx.x;
    const int bh = blockIdx.y;
    const int b = bh >> 3, h = bh & 7;
    const int tid = threadIdx.x;
    const int w = tid >> 6;
    const int l = tid & 63;
    const int lane16 = l & 15;
    const int quad = l >> 4;
    const size_t rowbase = (size_t)b * T_SEQ + (size_t)c * CHUNK_L;

    {
        const int dk0 = (tid >> 4) * 8;
        const int jb = (tid & 15) * 4;
        half8 r0 = *(const half8*)&Kf[(rowbase + jb + 0) * HIDDEN + h * DKV + dk0];
        half8 r1 = *(const half8*)&Kf[(rowbase + jb + 1) * HIDDEN + h * DKV + dk0];
        half8 r2 = *(const half8*)&Kf[(rowbase + jb + 2) * HIDDEN + h * DKV + dk0];
        half8 r3 = *(const half8*)&Kf[(rowbase + jb + 3) * HIDDEN + h * DKV + dk0];
#pragma unroll
        for (int dk = 0; dk < 8; ++dk) {
            HBits a0, a1, a2, a3;
            a0.h = r0[dk]; a1.h = r1[dk]; a2.h = r2[dk]; a3.h = r3[dk];
            unsigned int lo = ((unsigned int)a1.u << 16) | a0.u;
            unsigned int hi = ((unsigned int)a3.u << 16) | a2.u;
            *(unsigned int*)&kt[(dk0 + dk) * 72 + jb] = lo;
            *(unsigned int*)&kt[(dk0 + dk) * 72 + jb + 2] = hi;
        }
    }
    __syncthreads();

    const int m0 = (w >> 1) * 64;
    const int n0 = (w & 1) * 64;
    floatx4 acc[4][4];
#pragma unroll
    for (int i = 0; i < 4; ++i)
#pragma unroll
        for (int j = 0; j < 4; ++j)
            acc[i][j] = (floatx4){0.f, 0.f, 0.f, 0.f};

#pragma unroll
    for (int s = 0; s < 2; ++s) {
        half8 a[4], bb[4];
#pragma unroll
        for (int mt = 0; mt < 4; ++mt) {
            int dv = m0 + mt * 16 + lane16;
            a[mt] = *(const half8*)&VT[((size_t)bh * DKV + dv) * T_SEQ + c * CHUNK_L + s * 32 + quad * 8];
        }
#pragma unroll
        for (int nt = 0; nt < 4; ++nt)
            bb[nt] = *(const half8*)&kt[(n0 + nt * 16 + lane16) * 72 + s * 32 + quad * 8];
#pragma unroll
        for (int mt = 0; mt < 4; ++mt)
#pragma unroll
            for (int nt = 0; nt < 4; ++nt)
                acc[mt][nt] = __builtin_amdgcn_mfma_f32_16x16x32_f16(a[mt], bb[nt], acc[mt][nt], 0, 0, 0);
    }

    _Float16* Gp = G16 + ((size_t)bh * NCH + c) * (DKV * DKV);
#pragma unroll
    for (int mt = 0; mt < 4; ++mt)
#pragma unroll
        for (int nt = 0; nt < 4; ++nt)
#pragma unroll
            for (int r = 0; r < 4; ++r)
                Gp[(size_t)(m0 + mt * 16 + quad * 4 + r) * DKV + n0 + nt * 16 + lane16] =
                    (_Float16)acc[mt][nt][r];
}

// ---------------------------------------------------------------------------
// Exclusive prefix over chunks; fp32 running sum; Gh fp16 (scaled SCALE_P).
// ---------------------------------------------------------------------------
__global__ void prefix_kernel(const _Float16* __restrict__ G16, _Float16* __restrict__ Gh)
{
    int idx = blockIdx.x * 256 + threadIdx.x;   // 16 * 16384
    int bh = idx >> 14;
    int e = idx & 16383;
    const _Float16* p = G16 + (size_t)bh * NCH * 16384 + e;
    _Float16* q = Gh + (size_t)bh * NCH * 16384 + e;
    float run = 0.f;
#pragma unroll
    for (int c = 0; c < NCH; ++c) {
        q[(size_t)c * 16384] = (_Float16)(run * SCALE_P);
        run += (float)p[(size_t)c * 16384];
    }
}

// ---------------------------------------------------------------------------
// Attention per chunk, MFMA.
// ---------------------------------------------------------------------------
#define PSLD 40
__global__ __launch_bounds__(256) void attn_mfma(const _Float16* __restrict__ Qf,
                                                 const _Float16* __restrict__ Kf,
                                                 const _Float16* __restrict__ VT,
                                                 const _Float16* __restrict__ Gh,
                                                 _Float16* __restrict__ O)
{
    __shared__ _Float16 ps[2 * 64 * PSLD];
    const int c = blockIdx.x;
    const int bh = blockIdx.y;
    const int b = bh >> 3, h = bh & 7;
    const int tid = threadIdx.x;
    const int w = tid >> 6;
    const int l = tid & 63;
    const int lane16 = l & 15;
    const int quad = l >> 4;
    const size_t rowbase = (size_t)b * T_SEQ + (size_t)c * CHUNK_L;

    {
        const int m0 = (w >> 1) * 32;
        const int n0 = (w & 1) * 32;
        floatx4 aq[2][2];
#pragma unroll
        for (int i = 0; i < 2; ++i)
#pragma unroll
            for (int j = 0; j < 2; ++j)
                aq[i][j] = (floatx4){0.f, 0.f, 0.f, 0.f};
#pragma unroll
        for (int s = 0; s < 4; ++s) {
            half8 a[2], bb[2];
#pragma unroll
            for (int mt = 0; mt < 2; ++mt)
                a[mt] = *(const half8*)&Qf[(rowbase + m0 + mt * 16 + lane16) * HIDDEN +
                                           h * DKV + s * 32 + quad * 8];
#pragma unroll
            for (int nt = 0; nt < 2; ++nt)
                bb[nt] = *(const half8*)&Kf[(rowbase + n0 + nt * 16 + lane16) * HIDDEN +
                                            h * DKV + s * 32 + quad * 8];
#pragma unroll
            for (int mt = 0; mt < 2; ++mt)
#pragma unroll
                for (int nt = 0; nt < 2; ++nt)
                    aq[mt][nt] = __builtin_amdgcn_mfma_f32_16x16x32_f16(a[mt], bb[nt], aq[mt][nt], 0, 0, 0);
        }
#pragma unroll
        for (int mt = 0; mt < 2; ++mt)
#pragma unroll
            for (int nt = 0; nt < 2; ++nt) {
                int j = n0 + nt * 16 + lane16;
#pragma unroll
                for (int r = 0; r < 4; ++r) {
                    int i = m0 + mt * 16 + quad * 4 + r;
                    float v = (j <= i) ? aq[mt][nt][r] * SCALE_P : 0.f;
                    ps[(j >> 5) * 64 * PSLD + i * PSLD + (j & 31)] = (_Float16)v;
                }
            }
    }
    __syncthreads();

    const int n0o = w * 32;
    floatx4 accO[4][2];
#pragma unroll
    for (int i = 0; i < 4; ++i)
#pragma unroll
        for (int j = 0; j < 2; ++j)
            accO[i][j] = (floatx4){0.f, 0.f, 0.f, 0.f};

#pragma unroll
    for (int s = 0; s < 2; ++s) {
        half8 a[4], bb[2];
#pragma unroll
        for (int mt = 0; mt < 4; ++mt)
            a[mt] = *(const half8*)&ps[s * 64 * PSLD + (mt * 16 + lane16) * PSLD + quad * 8];
#pragma unroll
        for (int nt = 0; nt < 2; ++nt) {
            int dv = n0o + nt * 16 + lane16;
            bb[nt] = *(const half8*)&VT[((size_t)bh * DKV + dv) * T_SEQ + c * CHUNK_L + s * 32 + quad * 8];
        }
#pragma unroll
        for (int mt = 0; mt < 4; ++mt)
#pragma unroll
            for (int nt = 0; nt < 2; ++nt)
                accO[mt][nt] = __builtin_amdgcn_mfma_f32_16x16x32_f16(a[mt], bb[nt], accO[mt][nt], 0, 0, 0);
    }

    const _Float16* gh = Gh + ((size_t)bh * NCH + c) * (DKV * DKV);
#pragma unroll
    for (int s = 0; s < 4; ++s) {
        half8 a[4], bb[2];
#pragma unroll
        for (int mt = 0; mt < 4; ++mt)
            a[mt] = *(const half8*)&Qf[(rowbase + mt * 16 + lane16) * HIDDEN +
                                       h * DKV + s * 32 + quad * 8];
#pragma unroll
        for (int nt = 0; nt < 2; ++nt) {
            int dv = n0o + nt * 16 + lane16;
            bb[nt] = *(const half8*)&gh[(size_t)dv * DKV + s * 32 + quad * 8];
        }
#pragma unroll
        for (int mt = 0; mt < 4; ++mt)
#pragma unroll
            for (int nt = 0; nt < 2; ++nt)
                accO[mt][nt] = __builtin_amdgcn_mfma_f32_16x16x32_f16(a[mt], bb[nt], accO[mt][nt], 0, 0, 0);
    }

#pragma unroll
    for (int mt = 0; mt < 4; ++mt)
#pragma unroll
        for (int nt = 0; nt < 2; ++nt)
#pragma unroll
            for (int r = 0; r < 4; ++r)
                O[(rowbase + mt * 16 + quad * 4 + r) * HIDDEN + h * DKV + n0o + nt * 16 + lane16] =
                    (_Float16)(accO[mt][nt][r] * OEPS);
}

// ---------------------------------------------------------------------------
// Workspace map (192 MiB, fully DISJOINT — no aliasing hazards):
//   [0,16)    h16 (P0-P1) -> qf16 (P3-P6)   [h16 dead after P1]
//   [16,32)   weights (whole run)
//   [32,80)   qkvlin (P1-P3)
//   [80,96)   kf16 (P3-P6)
//   [96,112)  vT (P2-P6)
//   [112,128) O16 (P6-P7)
//   [128,160) G16 fp16 (P4-P5)
//   [160,192) Gh fp16 (P5-P6)
// ---------------------------------------------------------------------------
extern "C" void kernel_launch(void* const* d_in, const int* in_sizes, int n_in,
                              void* d_out, int out_size, void* d_ws, size_t ws_size,
                              hipStream_t stream)
{
    (void)in_sizes; (void)n_in; (void)out_size; (void)ws_size;
    const float* hs = (const float*)d_in[0];
    const float* wq = (const float*)d_in[1];
    const float* wk = (const float*)d_in[2];
    const float* wv = (const float*)d_in[3];
    const float* wo = (const float*)d_in[4];
    const float* cq = (const float*)d_in[5];
    const float* ck = (const float*)d_in[6];
    const float* cv = (const float*)d_in[7];
    const float* fmq_w1 = (const float*)d_in[8];
    const float* fmq_b1 = (const float*)d_in[9];
    const float* fmq_w2 = (const float*)d_in[10];
    const float* fmq_b2 = (const float*)d_in[11];
    const float* fmk_w1 = (const float*)d_in[12];
    const float* fmk_b1 = (const float*)d_in[13];
    const float* fmk_w2 = (const float*)d_in[14];
    const float* fmk_b2 = (const float*)d_in[15];
    float* out = (float*)d_out;
    char* ws = (char*)d_ws;

    const size_t MB = 1024 * 1024;
    _Float16* h16     = (_Float16*)(ws + 0);
    _Float16* qf16    = (_Float16*)(ws + 0);
    _Float16* wqkv16  = (_Float16*)(ws + 16 * MB);         // 3072x1024
    _Float16* wo16    = wqkv16 + (3 << 20);
    _Float16* fmw     = wqkv16 + (4 << 20);                // 4 x 16384
    _Float16* qkvlin  = (_Float16*)(ws + 32 * MB);         // [8192][3072]
    _Float16* kf16    = (_Float16*)(ws + 80 * MB);
    _Float16* vT      = (_Float16*)(ws + 96 * MB);
    _Float16* O16     = (_Float16*)(ws + 112 * MB);
    _Float16* G16     = (_Float16*)(ws + 128 * MB);        // 32 MB fp16
    _Float16* Gh      = (_Float16*)(ws + 160 * MB);        // 32 MB fp16

    // ---- P0: casts ----
    cast_f32_f16<<<4096, 256, 0, stream>>>(hs, h16, BT * HIDDEN / 8);
    cast8_f32_f16<<<dim3(512, 8), 256, 0, stream>>>(
        wq, wk, wv, wo, fmq_w1, fmq_w2, fmk_w1, fmk_w2,
        wqkv16, wqkv16 + (1 << 20), wqkv16 + (2 << 20), wo16,
        fmw, fmw + 16384, fmw + 2 * 16384, fmw + 3 * 16384,
        HIDDEN * HIDDEN / 8, DKV * DKV / 8);

    // ---- P1: fused QKV projection (N = 3072), 128x128 tiles, BK=64 ----
    dim3 gqkv(3 * HIDDEN / 128, BT / 128);   // (24, 64) = 1536 blocks
    gemm_nt_f16_h16<<<gqkv, 256, 0, stream>>>(h16, wqkv16, qkvlin, BT, 3 * HIDDEN, HIDDEN);

    // ---- P2: conv + silu for V (transposed out) ----
    conv_silu_T<<<2048, 256, 0, stream>>>(qkvlin + 2 * HIDDEN, 3 * HIDDEN, cv, vT);

    // ---- P3: FUSED conv + feature map for q,k ----
    dim3 fg(BT / 64, NHEAD, 2);
    convfm<<<fg, 256, 0, stream>>>(qkvlin, 3 * HIDDEN, cq, ck, fmw,
                                   fmq_b1, fmq_b2, fmk_b1, fmk_b2, qf16, kf16);

    // ---- P4-P6: chunked linear attention ----
    dim3 ag(NCH, BATCH * NHEAD);
    ktv_mfma<<<ag, 256, 0, stream>>>(kf16, vT, G16);
    prefix_kernel<<<(16 * 16384) / 256, 256, 0, stream>>>(G16, Gh);
    attn_mfma<<<ag, 256, 0, stream>>>(qf16, kf16, vT, Gh, O16);

    // ---- P7: output projection (undo SCALE_O), BK=64 ----
    dim3 gg(HIDDEN / 128, BT / 128);
    gemm_nt_f16_f32<<<gg, 256, 0, stream>>>(O16, wo16, out, BT, HIDDEN, HIDDEN, 1.0f / SCALE_O);
}

// Round 13
// 321.726 us; speedup vs baseline: 1.0643x; 1.0643x over previous
//
#include <hip/hip_runtime.h>
#include <cstdint>
#include <cstddef>

#define T_SEQ 4096
#define BATCH 2
#define HIDDEN 1024
#define NHEAD 8
#define DKV 128
#define BT (BATCH * T_SEQ)   // 8192
#define NCH 64               // chunks per batch
#define CHUNK_L 64
#define QSCALE 0.08838834764831845f
#define SCALE_P 1024.0f
#define SCALE_O 8192.0f
#define OEPS 0.7071067811865476f

typedef _Float16 half8 __attribute__((ext_vector_type(8)));
typedef float floatx4 __attribute__((ext_vector_type(4)));

union HBits { _Float16 h; unsigned short u; };

// ---------------------------------------------------------------------------
// fp32 -> fp16 cast, 8 elements/thread
// ---------------------------------------------------------------------------
__global__ void cast_f32_f16(const float* __restrict__ X, _Float16* __restrict__ Y, int n8)
{
    int idx = blockIdx.x * 256 + threadIdx.x;
    if (idx < n8) {
        float4 a = ((const float4*)X)[idx * 2];
        float4 b = ((const float4*)X)[idx * 2 + 1];
        half8 h = { (_Float16)a.x, (_Float16)a.y, (_Float16)a.z, (_Float16)a.w,
                    (_Float16)b.x, (_Float16)b.y, (_Float16)b.z, (_Float16)b.w };
        *(half8*)&Y[idx * 8] = h;
    }
}

// 8 weight tensors in one launch; blockIdx.y selects.
__global__ void cast8_f32_f16(const float* __restrict__ s0, const float* __restrict__ s1,
                              const float* __restrict__ s2, const float* __restrict__ s3,
                              const float* __restrict__ s4, const float* __restrict__ s5,
                              const float* __restrict__ s6, const float* __restrict__ s7,
                              _Float16* __restrict__ d0, _Float16* __restrict__ d1,
                              _Float16* __restrict__ d2, _Float16* __restrict__ d3,
                              _Float16* __restrict__ d4, _Float16* __restrict__ d5,
                              _Float16* __restrict__ d6, _Float16* __restrict__ d7,
                              int nbig, int nsmall)
{
    int sel = blockIdx.y;
    const float* src; _Float16* dst; int n8;
    switch (sel) {
        case 0: src = s0; dst = d0; n8 = nbig; break;
        case 1: src = s1; dst = d1; n8 = nbig; break;
        case 2: src = s2; dst = d2; n8 = nbig; break;
        case 3: src = s3; dst = d3; n8 = nbig; break;
        case 4: src = s4; dst = d4; n8 = nsmall; break;
        case 5: src = s5; dst = d5; n8 = nsmall; break;
        case 6: src = s6; dst = d6; n8 = nsmall; break;
        default: src = s7; dst = d7; n8 = nsmall; break;
    }
    int idx = blockIdx.x * 256 + threadIdx.x;
    if (idx < n8) {
        float4 u = ((const float4*)src)[idx * 2];
        float4 v = ((const float4*)src)[idx * 2 + 1];
        half8 h = { (_Float16)u.x, (_Float16)u.y, (_Float16)u.z, (_Float16)u.w,
                    (_Float16)v.x, (_Float16)v.y, (_Float16)v.z, (_Float16)v.w };
        *(half8*)&dst[idx * 8] = h;
    }
}

// ---------------------------------------------------------------------------
// GEMM (NT) fp16 MFMA, fp16 out: 128x128 tile, BK=64, 4 waves, XOR-swizzled
// LDS columns. Proven R8 structure: ~747 TF, 0 bank conflicts.
// ---------------------------------------------------------------------------
__global__ __launch_bounds__(256) void gemm_nt_f16_h16(const _Float16* __restrict__ A,
                                                       const _Float16* __restrict__ W,
                                                       _Float16* __restrict__ C,
                                                       int M, int N, int K)
{
    __shared__ _Float16 As[128 * 64];
    __shared__ _Float16 Ws[128 * 64];
    const int bm = blockIdx.y * 128;
    const int bn = blockIdx.x * 128;
    const int tid = threadIdx.x;
    const int w = tid >> 6;
    const int l = tid & 63;
    const int wm = (w >> 1) * 64;
    const int wn = (w & 1) * 64;
    const int lane16 = l & 15;
    const int quad = l >> 4;
    const int srow = w * 8 + (l >> 3);
    const int skh = ((l & 7) ^ (l >> 3)) * 8;
    const int rsw = lane16 & 7;

    floatx4 acc[4][4];
#pragma unroll
    for (int i = 0; i < 4; ++i)
#pragma unroll
        for (int j = 0; j < 4; ++j)
            acc[i][j] = (floatx4){0.f, 0.f, 0.f, 0.f};

    for (int k0 = 0; k0 < K; k0 += 64) {
#pragma unroll
        for (int c = 0; c < 4; ++c) {
            int row = c * 32 + srow;
            const _Float16* ga = A + (size_t)(bm + row) * K + k0 + skh;
            const _Float16* gw = W + (size_t)(bn + row) * K + k0 + skh;
            __builtin_amdgcn_global_load_lds(
                (const __attribute__((address_space(1))) void*)ga,
                (__attribute__((address_space(3))) void*)(As + c * 2048 + w * 512), 16, 0, 0);
            __builtin_amdgcn_global_load_lds(
                (const __attribute__((address_space(1))) void*)gw,
                (__attribute__((address_space(3))) void*)(Ws + c * 2048 + w * 512), 16, 0, 0);
        }
        __syncthreads();

#pragma unroll
        for (int s = 0; s < 2; ++s) {
            const int pc = (((s * 4 + quad) ^ rsw)) * 8;
            half8 a[4], b[4];
#pragma unroll
            for (int i = 0; i < 4; ++i) {
                a[i] = *(const half8*)&As[(wm + i * 16 + lane16) * 64 + pc];
                b[i] = *(const half8*)&Ws[(wn + i * 16 + lane16) * 64 + pc];
            }
#pragma unroll
            for (int i = 0; i < 4; ++i)
#pragma unroll
                for (int j = 0; j < 4; ++j)
                    acc[i][j] = __builtin_amdgcn_mfma_f32_16x16x32_f16(a[i], b[j], acc[i][j], 0, 0, 0);
        }
        __syncthreads();
    }
#pragma unroll
    for (int i = 0; i < 4; ++i)
#pragma unroll
        for (int j = 0; j < 4; ++j)
#pragma unroll
            for (int r = 0; r < 4; ++r)
                C[(size_t)(bm + wm + i * 16 + quad * 4 + r) * N + bn + wn + j * 16 + lane16] =
                    (_Float16)acc[i][j][r];
}

// ---------------------------------------------------------------------------
// Same BK=64 structure, fp32 out with scale (final projection; undoes SCALE_O).
// ---------------------------------------------------------------------------
__global__ __launch_bounds__(256) void gemm_nt_f16_f32(const _Float16* __restrict__ A,
                                                       const _Float16* __restrict__ W,
                                                       float* __restrict__ C,
                                                       int M, int N, int K, float scale)
{
    __shared__ _Float16 As[128 * 64];
    __shared__ _Float16 Ws[128 * 64];
    const int bm = blockIdx.y * 128;
    const int bn = blockIdx.x * 128;
    const int tid = threadIdx.x;
    const int w = tid >> 6;
    const int l = tid & 63;
    const int wm = (w >> 1) * 64;
    const int wn = (w & 1) * 64;
    const int lane16 = l & 15;
    const int quad = l >> 4;
    const int srow = w * 8 + (l >> 3);
    const int skh = ((l & 7) ^ (l >> 3)) * 8;
    const int rsw = lane16 & 7;

    floatx4 acc[4][4];
#pragma unroll
    for (int i = 0; i < 4; ++i)
#pragma unroll
        for (int j = 0; j < 4; ++j)
            acc[i][j] = (floatx4){0.f, 0.f, 0.f, 0.f};

    for (int k0 = 0; k0 < K; k0 += 64) {
#pragma unroll
        for (int c = 0; c < 4; ++c) {
            int row = c * 32 + srow;
            const _Float16* ga = A + (size_t)(bm + row) * K + k0 + skh;
            const _Float16* gw = W + (size_t)(bn + row) * K + k0 + skh;
            __builtin_amdgcn_global_load_lds(
                (const __attribute__((address_space(1))) void*)ga,
                (__attribute__((address_space(3))) void*)(As + c * 2048 + w * 512), 16, 0, 0);
            __builtin_amdgcn_global_load_lds(
                (const __attribute__((address_space(1))) void*)gw,
                (__attribute__((address_space(3))) void*)(Ws + c * 2048 + w * 512), 16, 0, 0);
        }
        __syncthreads();

#pragma unroll
        for (int s = 0; s < 2; ++s) {
            const int pc = (((s * 4 + quad) ^ rsw)) * 8;
            half8 a[4], b[4];
#pragma unroll
            for (int i = 0; i < 4; ++i) {
                a[i] = *(const half8*)&As[(wm + i * 16 + lane16) * 64 + pc];
                b[i] = *(const half8*)&Ws[(wn + i * 16 + lane16) * 64 + pc];
            }
#pragma unroll
            for (int i = 0; i < 4; ++i)
#pragma unroll
                for (int j = 0; j < 4; ++j)
                    acc[i][j] = __builtin_amdgcn_mfma_f32_16x16x32_f16(a[i], b[j], acc[i][j], 0, 0, 0);
        }
        __syncthreads();
    }
#pragma unroll
    for (int i = 0; i < 4; ++i)
#pragma unroll
        for (int j = 0; j < 4; ++j)
#pragma unroll
            for (int r = 0; r < 4; ++r)
                C[(size_t)(bm + wm + i * 16 + quad * 4 + r) * N + bn + wn + j * 16 + lane16] =
                    acc[i][j][r] * scale;
}

// ---------------------------------------------------------------------------
// Conv + SiLU for V, writing TRANSPOSED: vT[b*1024 + d][t]  (fp16).
// grid.x = 2048 = 64 ttiles * 16 dtiles * 2 batch.
// ---------------------------------------------------------------------------
__global__ __launch_bounds__(256) void conv_silu_T(const _Float16* __restrict__ X, int ldx,
                                                   const float* __restrict__ Wc,
                                                   _Float16* __restrict__ VT)
{
    __shared__ _Float16 xs[67 * 64];
    const int bx = blockIdx.x;
    const int t0 = (bx & 63) * 64;
    const int dt = ((bx >> 6) & 15) * 64;
    const int z = bx >> 10;
    const int tid = threadIdx.x;

#pragma unroll
    for (int i = 0; i < 3; ++i) {
        int p = tid + 256 * i;
        if (p < 536) {
            int row = p >> 3, d8 = (p & 7) * 8;
            int t = t0 - 3 + row;
            half8 v;
            if (t >= 0)
                v = *(const half8*)&X[((size_t)z * T_SEQ + t) * ldx + dt + d8];
            else
                v = (half8){0, 0, 0, 0, 0, 0, 0, 0};
            *(half8*)&xs[row * 64 + d8] = v;
        }
    }
    __syncthreads();

    const int d = tid & 63;
    const int dg = dt + d;
    float4 w = *(const float4*)&Wc[dg * 4];
#pragma unroll
    for (int u = 0; u < 2; ++u) {
        int tg = (tid >> 6) + u * 4;
        half8 o;
#pragma unroll
        for (int s = 0; s < 8; ++s) {
            int base = (tg * 8 + s + 3) * 64 + d;
            float acc = (float)xs[base] * w.w
                      + (float)xs[base - 64] * w.z
                      + (float)xs[base - 128] * w.y
                      + (float)xs[base - 192] * w.x;
            o[s] = (_Float16)(acc / (1.f + __expf(-acc)));
        }
        *(half8*)&VT[((size_t)z * HIDDEN + dg) * T_SEQ + t0 + tg * 8] = o;
    }
}

// ---------------------------------------------------------------------------
// FUSED conv+SiLU + feature map (q/k via blockIdx.z), v2.
// Conv thread mapping = (d-oct = tid&15, row-quad = tid>>4): each thread owns
// 8 channels x 4 rows, loads its 8 float4 conv weights ONCE (amortized) —
// fixes R11's per-output weight gather. Same fma order -> bit-identical.
// ---------------------------------------------------------------------------
#define XIN_LD 136   // 67 rows x 136 halfs
__global__ __launch_bounds__(256) void convfm(const _Float16* __restrict__ QKV, int ldx,
                                              const float* __restrict__ Wcq,
                                              const float* __restrict__ Wck,
                                              const _Float16* __restrict__ Wfm,  // 4x16384
                                              const float* __restrict__ Bq1,
                                              const float* __restrict__ Bq2,
                                              const float* __restrict__ Bk1,
                                              const float* __restrict__ Bk2,
                                              _Float16* __restrict__ OUTq,
                                              _Float16* __restrict__ OUTk)
{
    const int sel = blockIdx.z;
    const float* Wc = sel ? Wck : Wcq;
    const _Float16* W1h = Wfm + (sel ? 2 * 16384 : 0);
    const _Float16* W2h = Wfm + (sel ? 3 * 16384 : 16384);
    const float* B1 = sel ? Bk1 : Bq1;
    const float* B2 = sel ? Bk2 : Bq2;
    _Float16* OUT = sel ? OUTk : OUTq;

    __shared__ _Float16 xin[67 * XIN_LD];    // input window (t0-3 .. t0+63) x 128
    __shared__ _Float16 xs[4 * 64 * 32];     // conv output, MFMA staging layout
    const int t0 = blockIdx.x * 64;
    const int h = blockIdx.y;
    const int tid = threadIdx.x;
    const int w = tid >> 6;
    const int l = tid & 63;
    const int lane16 = l & 15;
    const int quad = l >> 4;
    const bool batch_start = (t0 & (T_SEQ - 1)) == 0;

    // ---- stage input window: 67 rows x 16 col-groups = 1072 half8 ----
    for (int p = tid; p < 67 * 16; p += 256) {
        int row = p >> 4, cg = p & 15;
        half8 v;
        if (batch_start && row < 3)
            v = (half8){0, 0, 0, 0, 0, 0, 0, 0};
        else
            v = *(const half8*)&QKV[(size_t)(t0 - 3 + row) * ldx + sel * HIDDEN + h * DKV + cg * 8];
        *(half8*)&xin[row * XIN_LD + cg * 8] = v;
    }
    __syncthreads();

    // ---- conv + silu: thread owns 8 channels (d-oct) x 4 rows ----
    {
        const int doct = tid & 15;       // d0 = doct*8
        const int d0 = doct * 8;
        const int rq = (tid >> 4) * 4;   // rows rq..rq+3
        const int u = doct >> 2;         // kstep slab in xs
        const int col = d0 & 31;

        float w0[8], w1[8], w2[8], w3[8];
#pragma unroll
        for (int e = 0; e < 8; ++e) {
            float4 wv = *(const float4*)&Wc[(h * DKV + d0 + e) * 4];
            w0[e] = wv.x; w1[e] = wv.y; w2[e] = wv.z; w3[e] = wv.w;
        }

#pragma unroll
        for (int rr = 0; rr < 4; ++rr) {
            const int row = rq + rr;
            half8 x3 = *(const half8*)&xin[(row + 0) * XIN_LD + d0];
            half8 x2 = *(const half8*)&xin[(row + 1) * XIN_LD + d0];
            half8 x1 = *(const half8*)&xin[(row + 2) * XIN_LD + d0];
            half8 x0 = *(const half8*)&xin[(row + 3) * XIN_LD + d0];
            half8 o;
#pragma unroll
            for (int e = 0; e < 8; ++e) {
                float acc = fmaf((float)x0[e], w3[e],
                            fmaf((float)x1[e], w2[e],
                            fmaf((float)x2[e], w1[e], (float)x3[e] * w0[e])));
                o[e] = (_Float16)(acc / (1.f + __expf(-acc)));
            }
            *(half8*)&xs[u * 2048 + row * 32 + col] = o;
        }
    }
    __syncthreads();

    // ---- dual GEMM + hadamard ----
    floatx4 acc1[4][2], acc2[4][2];
#pragma unroll
    for (int i = 0; i < 4; ++i)
#pragma unroll
        for (int j = 0; j < 2; ++j) {
            acc1[i][j] = (floatx4){0.f, 0.f, 0.f, 0.f};
            acc2[i][j] = (floatx4){0.f, 0.f, 0.f, 0.f};
        }

#pragma unroll
    for (int s = 0; s < 4; ++s) {
        half8 a[4];
#pragma unroll
        for (int mt = 0; mt < 4; ++mt)
            a[mt] = *(const half8*)&xs[s * 2048 + (mt * 16 + lane16) * 32 + quad * 8];
#pragma unroll
        for (int nt = 0; nt < 2; ++nt) {
            int e = w * 32 + nt * 16 + lane16;
            half8 b1 = *(const half8*)&W1h[(size_t)e * DKV + s * 32 + quad * 8];
            half8 b2 = *(const half8*)&W2h[(size_t)e * DKV + s * 32 + quad * 8];
#pragma unroll
            for (int mt = 0; mt < 4; ++mt) {
                acc1[mt][nt] = __builtin_amdgcn_mfma_f32_16x16x32_f16(a[mt], b1, acc1[mt][nt], 0, 0, 0);
                acc2[mt][nt] = __builtin_amdgcn_mfma_f32_16x16x32_f16(a[mt], b2, acc2[mt][nt], 0, 0, 0);
            }
        }
    }

#pragma unroll
    for (int nt = 0; nt < 2; ++nt) {
        int e = w * 32 + nt * 16 + lane16;
        float b1v = B1[e], b2v = B2[e];
#pragma unroll
        for (int mt = 0; mt < 4; ++mt)
#pragma unroll
            for (int r = 0; r < 4; ++r) {
                float o = (acc1[mt][nt][r] + b1v) * (acc2[mt][nt][r] + b2v);
                OUT[(size_t)(t0 + mt * 16 + quad * 4 + r) * HIDDEN + h * DKV + e] = (_Float16)o;
            }
    }
}

// ---------------------------------------------------------------------------
// Per-chunk S^T[dv][dk] = sum_j V[j][dv] K[j][dk], MFMA. fp16 out.
// ---------------------------------------------------------------------------
__global__ __launch_bounds__(256) void ktv_mfma(const _Float16* __restrict__ Kf,
                                                const _Float16* __restrict__ VT,
                                                _Float16* __restrict__ G16)
{
    __shared__ _Float16 kt[128 * 72];
    const int c = blockIdx.x;
    const int bh = blockIdx.y;
    const int b = bh >> 3, h = bh & 7;
    const int tid = threadIdx.x;
    const int w = tid >> 6;
    const int l = tid & 63;
    const int lane16 = l & 15;
    const int quad = l >> 4;
    const size_t rowbase = (size_t)b * T_SEQ + (size_t)c * CHUNK_L;

    {
        const int dk0 = (tid >> 4) * 8;
        const int jb = (tid & 15) * 4;
        half8 r0 = *(const half8*)&Kf[(rowbase + jb + 0) * HIDDEN + h * DKV + dk0];
        half8 r1 = *(const half8*)&Kf[(rowbase + jb + 1) * HIDDEN + h * DKV + dk0];
        half8 r2 = *(const half8*)&Kf[(rowbase + jb + 2) * HIDDEN + h * DKV + dk0];
        half8 r3 = *(const half8*)&Kf[(rowbase + jb + 3) * HIDDEN + h * DKV + dk0];
#pragma unroll
        for (int dk = 0; dk < 8; ++dk) {
            HBits a0, a1, a2, a3;
            a0.h = r0[dk]; a1.h = r1[dk]; a2.h = r2[dk]; a3.h = r3[dk];
            unsigned int lo = ((unsigned int)a1.u << 16) | a0.u;
            unsigned int hi = ((unsigned int)a3.u << 16) | a2.u;
            *(unsigned int*)&kt[(dk0 + dk) * 72 + jb] = lo;
            *(unsigned int*)&kt[(dk0 + dk) * 72 + jb + 2] = hi;
        }
    }
    __syncthreads();

    const int m0 = (w >> 1) * 64;
    const int n0 = (w & 1) * 64;
    floatx4 acc[4][4];
#pragma unroll
    for (int i = 0; i < 4; ++i)
#pragma unroll
        for (int j = 0; j < 4; ++j)
            acc[i][j] = (floatx4){0.f, 0.f, 0.f, 0.f};

#pragma unroll
    for (int s = 0; s < 2; ++s) {
        half8 a[4], bb[4];
#pragma unroll
        for (int mt = 0; mt < 4; ++mt) {
            int dv = m0 + mt * 16 + lane16;
            a[mt] = *(const half8*)&VT[((size_t)bh * DKV + dv) * T_SEQ + c * CHUNK_L + s * 32 + quad * 8];
        }
#pragma unroll
        for (int nt = 0; nt < 4; ++nt)
            bb[nt] = *(const half8*)&kt[(n0 + nt * 16 + lane16) * 72 + s * 32 + quad * 8];
#pragma unroll
        for (int mt = 0; mt < 4; ++mt)
#pragma unroll
            for (int nt = 0; nt < 4; ++nt)
                acc[mt][nt] = __builtin_amdgcn_mfma_f32_16x16x32_f16(a[mt], bb[nt], acc[mt][nt], 0, 0, 0);
    }

    _Float16* Gp = G16 + ((size_t)bh * NCH + c) * (DKV * DKV);
#pragma unroll
    for (int mt = 0; mt < 4; ++mt)
#pragma unroll
        for (int nt = 0; nt < 4; ++nt)
#pragma unroll
            for (int r = 0; r < 4; ++r)
                Gp[(size_t)(m0 + mt * 16 + quad * 4 + r) * DKV + n0 + nt * 16 + lane16] =
                    (_Float16)acc[mt][nt][r];
}

// ---------------------------------------------------------------------------
// Exclusive prefix over chunks; fp32 running sum; Gh fp16 (scaled SCALE_P).
// ---------------------------------------------------------------------------
__global__ void prefix_kernel(const _Float16* __restrict__ G16, _Float16* __restrict__ Gh)
{
    int idx = blockIdx.x * 256 + threadIdx.x;   // 16 * 16384
    int bh = idx >> 14;
    int e = idx & 16383;
    const _Float16* p = G16 + (size_t)bh * NCH * 16384 + e;
    _Float16* q = Gh + (size_t)bh * NCH * 16384 + e;
    float run = 0.f;
#pragma unroll
    for (int c = 0; c < NCH; ++c) {
        q[(size_t)c * 16384] = (_Float16)(run * SCALE_P);
        run += (float)p[(size_t)c * 16384];
    }
}

// ---------------------------------------------------------------------------
// Attention per chunk, MFMA.
// ---------------------------------------------------------------------------
#define PSLD 40
__global__ __launch_bounds__(256) void attn_mfma(const _Float16* __restrict__ Qf,
                                                 const _Float16* __restrict__ Kf,
                                                 const _Float16* __restrict__ VT,
                                                 const _Float16* __restrict__ Gh,
                                                 _Float16* __restrict__ O)
{
    __shared__ _Float16 ps[2 * 64 * PSLD];
    const int c = blockIdx.x;
    const int bh = blockIdx.y;
    const int b = bh >> 3, h = bh & 7;
    const int tid = threadIdx.x;
    const int w = tid >> 6;
    const int l = tid & 63;
    const int lane16 = l & 15;
    const int quad = l >> 4;
    const size_t rowbase = (size_t)b * T_SEQ + (size_t)c * CHUNK_L;

    {
        const int m0 = (w >> 1) * 32;
        const int n0 = (w & 1) * 32;
        floatx4 aq[2][2];
#pragma unroll
        for (int i = 0; i < 2; ++i)
#pragma unroll
            for (int j = 0; j < 2; ++j)
                aq[i][j] = (floatx4){0.f, 0.f, 0.f, 0.f};
#pragma unroll
        for (int s = 0; s < 4; ++s) {
            half8 a[2], bb[2];
#pragma unroll
            for (int mt = 0; mt < 2; ++mt)
                a[mt] = *(const half8*)&Qf[(rowbase + m0 + mt * 16 + lane16) * HIDDEN +
                                           h * DKV + s * 32 + quad * 8];
#pragma unroll
            for (int nt = 0; nt < 2; ++nt)
                bb[nt] = *(const half8*)&Kf[(rowbase + n0 + nt * 16 + lane16) * HIDDEN +
                                            h * DKV + s * 32 + quad * 8];
#pragma unroll
            for (int mt = 0; mt < 2; ++mt)
#pragma unroll
                for (int nt = 0; nt < 2; ++nt)
                    aq[mt][nt] = __builtin_amdgcn_mfma_f32_16x16x32_f16(a[mt], bb[nt], aq[mt][nt], 0, 0, 0);
        }
#pragma unroll
        for (int mt = 0; mt < 2; ++mt)
#pragma unroll
            for (int nt = 0; nt < 2; ++nt) {
                int j = n0 + nt * 16 + lane16;
#pragma unroll
                for (int r = 0; r < 4; ++r) {
                    int i = m0 + mt * 16 + quad * 4 + r;
                    float v = (j <= i) ? aq[mt][nt][r] * SCALE_P : 0.f;
                    ps[(j >> 5) * 64 * PSLD + i * PSLD + (j & 31)] = (_Float16)v;
                }
            }
    }
    __syncthreads();

    const int n0o = w * 32;
    floatx4 accO[4][2];
#pragma unroll
    for (int i = 0; i < 4; ++i)
#pragma unroll
        for (int j = 0; j < 2; ++j)
            accO[i][j] = (floatx4){0.f, 0.f, 0.f, 0.f};

#pragma unroll
    for (int s = 0; s < 2; ++s) {
        half8 a[4], bb[2];
#pragma unroll
        for (int mt = 0; mt < 4; ++mt)
            a[mt] = *(const half8*)&ps[s * 64 * PSLD + (mt * 16 + lane16) * PSLD + quad * 8];
#pragma unroll
        for (int nt = 0; nt < 2; ++nt) {
            int dv = n0o + nt * 16 + lane16;
            bb[nt] = *(const half8*)&VT[((size_t)bh * DKV + dv) * T_SEQ + c * CHUNK_L + s * 32 + quad * 8];
        }
#pragma unroll
        for (int mt = 0; mt < 4; ++mt)
#pragma unroll
            for (int nt = 0; nt < 2; ++nt)
                accO[mt][nt] = __builtin_amdgcn_mfma_f32_16x16x32_f16(a[mt], bb[nt], accO[mt][nt], 0, 0, 0);
    }

    const _Float16* gh = Gh + ((size_t)bh * NCH + c) * (DKV * DKV);
#pragma unroll
    for (int s = 0; s < 4; ++s) {
        half8 a[4], bb[2];
#pragma unroll
        for (int mt = 0; mt < 4; ++mt)
            a[mt] = *(const half8*)&Qf[(rowbase + mt * 16 + lane16) * HIDDEN +
                                       h * DKV + s * 32 + quad * 8];
#pragma unroll
        for (int nt = 0; nt < 2; ++nt) {
            int dv = n0o + nt * 16 + lane16;
            bb[nt] = *(const half8*)&gh[(size_t)dv * DKV + s * 32 + quad * 8];
        }
#pragma unroll
        for (int mt = 0; mt < 4; ++mt)
#pragma unroll
            for (int nt = 0; nt < 2; ++nt)
                accO[mt][nt] = __builtin_amdgcn_mfma_f32_16x16x32_f16(a[mt], bb[nt], accO[mt][nt], 0, 0, 0);
    }

#pragma unroll
    for (int mt = 0; mt < 4; ++mt)
#pragma unroll
        for (int nt = 0; nt < 2; ++nt)
#pragma unroll
            for (int r = 0; r < 4; ++r)
                O[(rowbase + mt * 16 + quad * 4 + r) * HIDDEN + h * DKV + n0o + nt * 16 + lane16] =
                    (_Float16)(accO[mt][nt][r] * OEPS);
}

// ---------------------------------------------------------------------------
// Workspace map (192 MiB, fully DISJOINT):
//   [0,16)    h16 (P0-P1) -> qf16 (P3-P6)
//   [16,32)   weights (whole run)
//   [32,80)   qkvlin (P1-P3)
//   [80,96)   kf16 (P3-P6)
//   [96,112)  vT (P2-P6)
//   [112,128) O16 (P6-P7)
//   [128,160) G16 fp16 (P4-P5)
//   [160,192) Gh fp16 (P5-P6)
// ---------------------------------------------------------------------------
extern "C" void kernel_launch(void* const* d_in, const int* in_sizes, int n_in,
                              void* d_out, int out_size, void* d_ws, size_t ws_size,
                              hipStream_t stream)
{
    (void)in_sizes; (void)n_in; (void)out_size; (void)ws_size;
    const float* hs = (const float*)d_in[0];
    const float* wq = (const float*)d_in[1];
    const float* wk = (const float*)d_in[2];
    const float* wv = (const float*)d_in[3];
    const float* wo = (const float*)d_in[4];
    const float* cq = (const float*)d_in[5];
    const float* ck = (const float*)d_in[6];
    const float* cv = (const float*)d_in[7];
    const float* fmq_w1 = (const float*)d_in[8];
    const float* fmq_b1 = (const float*)d_in[9];
    const float* fmq_w2 = (const float*)d_in[10];
    const float* fmq_b2 = (const float*)d_in[11];
    const float* fmk_w1 = (const float*)d_in[12];
    const float* fmk_b1 = (const float*)d_in[13];
    const float* fmk_w2 = (const float*)d_in[14];
    const float* fmk_b2 = (const float*)d_in[15];
    float* out = (float*)d_out;
    char* ws = (char*)d_ws;

    const size_t MB = 1024 * 1024;
    _Float16* h16     = (_Float16*)(ws + 0);
    _Float16* qf16    = (_Float16*)(ws + 0);
    _Float16* wqkv16  = (_Float16*)(ws + 16 * MB);         // 3072x1024
    _Float16* wo16    = wqkv16 + (3 << 20);
    _Float16* fmw     = wqkv16 + (4 << 20);                // 4 x 16384
    _Float16* qkvlin  = (_Float16*)(ws + 32 * MB);         // [8192][3072]
    _Float16* kf16    = (_Float16*)(ws + 80 * MB);
    _Float16* vT      = (_Float16*)(ws + 96 * MB);
    _Float16* O16     = (_Float16*)(ws + 112 * MB);
    _Float16* G16     = (_Float16*)(ws + 128 * MB);        // 32 MB fp16
    _Float16* Gh      = (_Float16*)(ws + 160 * MB);        // 32 MB fp16

    // ---- P0: casts ----
    cast_f32_f16<<<4096, 256, 0, stream>>>(hs, h16, BT * HIDDEN / 8);
    cast8_f32_f16<<<dim3(512, 8), 256, 0, stream>>>(
        wq, wk, wv, wo, fmq_w1, fmq_w2, fmk_w1, fmk_w2,
        wqkv16, wqkv16 + (1 << 20), wqkv16 + (2 << 20), wo16,
        fmw, fmw + 16384, fmw + 2 * 16384, fmw + 3 * 16384,
        HIDDEN * HIDDEN / 8, DKV * DKV / 8);

    // ---- P1: fused QKV projection (N = 3072), 128x128 tiles, BK=64 ----
    dim3 gqkv(3 * HIDDEN / 128, BT / 128);   // (24, 64) = 1536 blocks
    gemm_nt_f16_h16<<<gqkv, 256, 0, stream>>>(h16, wqkv16, qkvlin, BT, 3 * HIDDEN, HIDDEN);

    // ---- P2: conv + silu for V (transposed out) ----
    conv_silu_T<<<2048, 256, 0, stream>>>(qkvlin + 2 * HIDDEN, 3 * HIDDEN, cv, vT);

    // ---- P3: FUSED conv + feature map for q,k (v2 weight-amortized) ----
    dim3 fg(BT / 64, NHEAD, 2);
    convfm<<<fg, 256, 0, stream>>>(qkvlin, 3 * HIDDEN, cq, ck, fmw,
                                   fmq_b1, fmq_b2, fmk_b1, fmk_b2, qf16, kf16);

    // ---- P4-P6: chunked linear attention ----
    dim3 ag(NCH, BATCH * NHEAD);
    ktv_mfma<<<ag, 256, 0, stream>>>(kf16, vT, G16);
    prefix_kernel<<<(16 * 16384) / 256, 256, 0, stream>>>(G16, Gh);
    attn_mfma<<<ag, 256, 0, stream>>>(qf16, kf16, vT, Gh, O16);

    // ---- P7: output projection (undo SCALE_O), BK=64 ----
    dim3 gg(HIDDEN / 128, BT / 128);
    gemm_nt_f16_f32<<<gg, 256, 0, stream>>>(O16, wo16, out, BT, HIDDEN, HIDDEN, 1.0f / SCALE_O);
}